// Round 1
// baseline (464.907 us; speedup 1.0000x reference)
//
#include <hip/hip_runtime.h>

#define SEQ 512
#define EMB 8
#define NFAC 4

// ---------------------------------------------------------------------------
// Precompute (batch-independent): self-attention over Q, then fold the
// cross-attn query heads through the K-projection:
//   wkq[p=h*4+f][e] = 0.5 * sum_d qc[f][h*4+d] * Wk_ca[h*4+d][e]
//   csb[p]          = 0.5 * sum_d qc[f][h*4+d] * bk_ca[h*4+d]
// so cross scores[p][s] = wkq[p] . x[s] + csb[p].
// ws layout: wkq[64], csb[8]  (72 floats)
// ---------------------------------------------------------------------------
__global__ void precompute_kernel(
    const float* __restrict__ Q,
    const float* __restrict__ sa_w_in, const float* __restrict__ sa_b_in,
    const float* __restrict__ sa_w_out, const float* __restrict__ sa_b_out,
    const float* __restrict__ ca_w_in, const float* __restrict__ ca_b_in,
    float* __restrict__ ws)
{
    if (threadIdx.x != 0 || blockIdx.x != 0) return;
    float qh[4][8], kh[4][8], vh[4][8];
    for (int l = 0; l < 4; ++l)
        for (int j = 0; j < 8; ++j) {
            float aq = sa_b_in[j], ak = sa_b_in[8 + j], av = sa_b_in[16 + j];
            for (int e = 0; e < 8; ++e) {
                float q = Q[l * 8 + e];
                aq += q * sa_w_in[j * 8 + e];
                ak += q * sa_w_in[(8 + j) * 8 + e];
                av += q * sa_w_in[(16 + j) * 8 + e];
            }
            qh[l][j] = aq; kh[l][j] = ak; vh[l][j] = av;
        }
    float ctxf[4][8];
    for (int h = 0; h < 2; ++h)
        for (int l = 0; l < 4; ++l) {
            float sc[4];
            float mx = -1e30f;
            for (int m = 0; m < 4; ++m) {
                float a = 0.f;
                for (int d = 0; d < 4; ++d) a += qh[l][h*4+d] * kh[m][h*4+d];
                sc[m] = 0.5f * a;
                mx = fmaxf(mx, sc[m]);
            }
            float ssum = 0.f;
            for (int m = 0; m < 4; ++m) { sc[m] = __expf(sc[m] - mx); ssum += sc[m]; }
            for (int d = 0; d < 4; ++d) {
                float a = 0.f;
                for (int m = 0; m < 4; ++m) a += sc[m] * vh[m][h*4+d];
                ctxf[l][h*4+d] = a / ssum;
            }
        }
    float Qu[4][8];
    for (int l = 0; l < 4; ++l)
        for (int e2 = 0; e2 < 8; ++e2) {
            float a = sa_b_out[e2];
            for (int e = 0; e < 8; ++e) a += ctxf[l][e] * sa_w_out[e2 * 8 + e];
            Qu[l][e2] = a;
        }
    float qc[4][8];  // [f][h*4+d] = cross-attn query heads
    for (int l = 0; l < 4; ++l)
        for (int j = 0; j < 8; ++j) {
            float a = ca_b_in[j];
            for (int e = 0; e < 8; ++e) a += Qu[l][e] * ca_w_in[j * 8 + e];
            qc[l][j] = a;
        }
    for (int h = 0; h < 2; ++h)
        for (int f = 0; f < 4; ++f) {
            int p = h * 4 + f;
            for (int e = 0; e < 8; ++e) {
                float a = 0.f;
                for (int d = 0; d < 4; ++d) a += qc[f][h*4+d] * ca_w_in[(8 + h*4+d) * 8 + e];
                ws[p * 8 + e] = 0.5f * a;
            }
            float a = 0.f;
            for (int d = 0; d < 4; ++d) a += qc[f][h*4+d] * ca_b_in[8 + h*4+d];
            ws[64 + p] = 0.5f * a;
        }
}

// ---------------------------------------------------------------------------
// Main fused kernel: one block per batch, 256 threads = 4 waves.
// Wave w owns cross-score rows p={2w,2w+1} (h=w>>1), then sim row f=w.
// Lane l owns positions s = l + 64j (j=0..7), x cached in registers.
// Softmax fused into reductions (no max-subtract needed; exp args bounded).
// ---------------------------------------------------------------------------
__global__ __launch_bounds__(256, 2) void fused_kernel(
    const float* __restrict__ x,
    const float* __restrict__ ca_w_in, const float* __restrict__ ca_b_in,
    const float* __restrict__ ca_w_out, const float* __restrict__ ca_b_out,
    const float* __restrict__ r_w1, const float* __restrict__ r_b1,
    const float* __restrict__ r_w2, const float* __restrict__ r_b2,
    const float* __restrict__ ws,
    float* __restrict__ out, float* __restrict__ sim_out)
{
    const int b = blockIdx.x;
    const int tid = threadIdx.x;
    const int w = __builtin_amdgcn_readfirstlane(tid >> 6);
    const int lane = tid & 63;

    __shared__ float4 sctx4[8];   // normalized ctx rows [p][d0..d3]
    __shared__ float sff[4][8];   // final_factors [f][e]

    const float* xb = x + (size_t)b * (SEQ * EMB);

    // wave-uniform weights -> SGPRs (indices derived from readfirstlane)
    const int p0 = 2 * w, p1 = 2 * w + 1;
    const int h = w >> 1;
    float wq0[8], wq1[8], wvv[4][8], bv[4];
    #pragma unroll
    for (int e = 0; e < 8; ++e) { wq0[e] = ws[p0 * 8 + e]; wq1[e] = ws[p1 * 8 + e]; }
    const float cb0 = ws[64 + p0], cb1 = ws[64 + p1];
    #pragma unroll
    for (int d = 0; d < 4; ++d) {
        bv[d] = ca_b_in[16 + h * 4 + d];
        #pragma unroll
        for (int e = 0; e < 8; ++e) wvv[d][e] = ca_w_in[(16 + h * 4 + d) * 8 + e];
    }

    // ---- phase A: x load + cross scores + exp + V-proj + online ctx accum
    float xr[8][8];
    float acc0[4] = {0.f, 0.f, 0.f, 0.f}, acc1[4] = {0.f, 0.f, 0.f, 0.f};
    float sum0 = 0.f, sum1 = 0.f;
    #pragma unroll
    for (int j = 0; j < 8; ++j) {
        const int s = lane + 64 * j;
        const float4* xp = (const float4*)(xb + s * 8);
        float4 lo = xp[0], hi = xp[1];
        xr[j][0] = lo.x; xr[j][1] = lo.y; xr[j][2] = lo.z; xr[j][3] = lo.w;
        xr[j][4] = hi.x; xr[j][5] = hi.y; xr[j][6] = hi.z; xr[j][7] = hi.w;
        float sc0 = cb0, sc1 = cb1;
        #pragma unroll
        for (int e = 0; e < 8; ++e) { sc0 += wq0[e] * xr[j][e]; sc1 += wq1[e] * xr[j][e]; }
        float e0 = __expf(sc0), e1 = __expf(sc1);
        sum0 += e0; sum1 += e1;
        #pragma unroll
        for (int d = 0; d < 4; ++d) {
            float vh = bv[d];
            #pragma unroll
            for (int e = 0; e < 8; ++e) vh += wvv[d][e] * xr[j][e];
            acc0[d] += e0 * vh;
            acc1[d] += e1 * vh;
        }
    }
    // butterfly reduce 10 accumulators across the wave
    #pragma unroll
    for (int m = 1; m < 64; m <<= 1) {
        sum0 += __shfl_xor(sum0, m, 64);
        sum1 += __shfl_xor(sum1, m, 64);
        #pragma unroll
        for (int d = 0; d < 4; ++d) {
            acc0[d] += __shfl_xor(acc0[d], m, 64);
            acc1[d] += __shfl_xor(acc1[d], m, 64);
        }
    }
    if (lane == 0) {
        float i0 = 1.f / sum0, i1 = 1.f / sum1;
        sctx4[p0] = make_float4(acc0[0] * i0, acc0[1] * i0, acc0[2] * i0, acc0[3] * i0);
        sctx4[p1] = make_float4(acc1[0] * i1, acc1[1] * i1, acc1[2] * i1, acc1[3] * i1);
    }
    __syncthreads();

    // ---- phase B: Q_cross row f=w (redundant per lane; weights via s_load)
    float4 c0 = sctx4[w];       // h=0 part (p=w)
    float4 c1 = sctx4[4 + w];   // h=1 part (p=4+w)
    float qcr[8];
    #pragma unroll
    for (int e = 0; e < 8; ++e) {
        qcr[e] = ca_b_out[e]
            + c0.x * ca_w_out[e*8+0] + c0.y * ca_w_out[e*8+1]
            + c0.z * ca_w_out[e*8+2] + c0.w * ca_w_out[e*8+3]
            + c1.x * ca_w_out[e*8+4] + c1.y * ca_w_out[e*8+5]
            + c1.z * ca_w_out[e*8+6] + c1.w * ca_w_out[e*8+7];
    }

    // ---- phase C: similarity row f=w, write raw sim, fused softmax + ff
    float facc[8] = {0.f,0.f,0.f,0.f,0.f,0.f,0.f,0.f};
    float fsum = 0.f;
    float* simb = sim_out + (size_t)b * (NFAC * SEQ) + w * SEQ;
    #pragma unroll
    for (int j = 0; j < 8; ++j) {
        const int s = lane + 64 * j;
        float sim = 0.f;
        #pragma unroll
        for (int e = 0; e < 8; ++e) sim += qcr[e] * xr[j][e];
        simb[s] = sim;
        float ez = __expf(sim);
        fsum += ez;
        #pragma unroll
        for (int e = 0; e < 8; ++e) facc[e] += ez * xr[j][e];
    }
    #pragma unroll
    for (int m = 1; m < 64; m <<= 1) {
        fsum += __shfl_xor(fsum, m, 64);
        #pragma unroll
        for (int e = 0; e < 8; ++e) facc[e] += __shfl_xor(facc[e], m, 64);
    }
    if (lane == 0) {
        float inv = 1.f / fsum;
        #pragma unroll
        for (int e = 0; e < 8; ++e) sff[w][e] = facc[e] * inv;
    }
    __syncthreads();

    // ---- phase D: tiny MLP (wave 0, lanes 0..15), out[b]
    if (tid < 16) {
        float a = r_b1[tid];
        const float* fusedp = &sff[0][0];
        const float4* w1p = (const float4*)(r_w1 + tid * 32);
        #pragma unroll
        for (int k = 0; k < 8; ++k) {
            float4 ww = w1p[k];
            a += ww.x * fusedp[4*k+0] + ww.y * fusedp[4*k+1]
               + ww.z * fusedp[4*k+2] + ww.w * fusedp[4*k+3];
        }
        a = fmaxf(a, 0.f);
        float v = a * r_w2[tid];
        v += __shfl_xor(v, 1, 64);
        v += __shfl_xor(v, 2, 64);
        v += __shfl_xor(v, 4, 64);
        v += __shfl_xor(v, 8, 64);
        if (tid == 0) out[b] = v + r_b2[0];
    }
}

extern "C" void kernel_launch(void* const* d_in, const int* in_sizes, int n_in,
                              void* d_out, int out_size, void* d_ws, size_t ws_size,
                              hipStream_t stream) {
    const float* x        = (const float*)d_in[0];
    const float* Q        = (const float*)d_in[1];
    const float* sa_w_in  = (const float*)d_in[2];
    const float* sa_b_in  = (const float*)d_in[3];
    const float* sa_w_out = (const float*)d_in[4];
    const float* sa_b_out = (const float*)d_in[5];
    const float* ca_w_in  = (const float*)d_in[6];
    const float* ca_b_in  = (const float*)d_in[7];
    const float* ca_w_out = (const float*)d_in[8];
    const float* ca_b_out = (const float*)d_in[9];
    const float* r_w1     = (const float*)d_in[10];
    const float* r_b1     = (const float*)d_in[11];
    const float* r_w2     = (const float*)d_in[12];
    const float* r_b2     = (const float*)d_in[13];

    float* out = (float*)d_out;
    const int B = in_sizes[0] / (SEQ * EMB);
    float* sim = out + B;            // d_out = [out (B), similarity (B*F*S)]
    float* ws  = (float*)d_ws;       // 72 floats: wkq[64], csb[8]

    precompute_kernel<<<1, 64, 0, stream>>>(Q, sa_w_in, sa_b_in, sa_w_out, sa_b_out,
                                            ca_w_in, ca_b_in, ws);
    fused_kernel<<<B, 256, 0, stream>>>(x, ca_w_in, ca_b_in, ca_w_out, ca_b_out,
                                        r_w1, r_b1, r_w2, r_b2, ws, out, sim);
}